// Round 1
// baseline (997.934 us; speedup 1.0000x reference)
//
#include <hip/hip_runtime.h>
#include <hip/hip_bf16.h>
#include <cmath>
#include <cstdint>

using bf16 = __hip_bfloat16;
typedef __attribute__((ext_vector_type(8))) short short8;
typedef __attribute__((ext_vector_type(4))) float f32x4;
typedef __attribute__((ext_vector_type(4))) unsigned short ushort4v;

#define T_DIM 2048
#define B_DIM 8
#define D_DIM 1024
#define MROWS (T_DIM*B_DIM)   // 16384
#define N8 (B_DIM*D_DIM)      // 8192

__device__ __forceinline__ float b2f(bf16 x) { return __bfloat162float(x); }
__device__ __forceinline__ bf16  f2b(float x) { return __float2bfloat16(x); }
__device__ __forceinline__ float us2f(unsigned short u) {
    union { unsigned int i; float f; } x; x.i = ((unsigned int)u) << 16; return x.f;
}
__device__ __forceinline__ unsigned short f2us(float f) {
    bf16 b = __float2bfloat16(f);
    return *(unsigned short*)&b;
}

// async global->LDS, 16B per lane. LDS dest must be wave-uniform-base + lane*16.
__device__ __forceinline__ void gload_lds16(const bf16* g, bf16* l) {
    __builtin_amdgcn_global_load_lds(
        (const __attribute__((address_space(1))) unsigned int*)g,
        (__attribute__((address_space(3))) unsigned int*)l,
        16, 0, 0);
}

// ---------------- LayerNorm: f32 [16384,1024] -> bf16 ----------------
__global__ __launch_bounds__(256) void ln_kernel(const float* __restrict__ x,
                                                 bf16* __restrict__ h) {
    const int row = blockIdx.x;
    const int tid = threadIdx.x;
    const float4 v = ((const float4*)(x + (size_t)row * D_DIM))[tid];
    float s1 = v.x + v.y + v.z + v.w;
    float s2 = v.x*v.x + v.y*v.y + v.z*v.z + v.w*v.w;
    #pragma unroll
    for (int off = 32; off > 0; off >>= 1) {
        s1 += __shfl_down(s1, off);
        s2 += __shfl_down(s2, off);
    }
    __shared__ float red[8];
    const int lane = tid & 63, wv = tid >> 6;
    if (lane == 0) { red[wv*2] = s1; red[wv*2+1] = s2; }
    __syncthreads();
    s1 = red[0] + red[2] + red[4] + red[6];
    s2 = red[1] + red[3] + red[5] + red[7];
    const float mean = s1 * (1.0f / D_DIM);
    const float var  = s2 * (1.0f / D_DIM) - mean * mean;
    const float rstd = rsqrtf(var + 1.1754943508222875e-38f);
    bf16* hr = h + (size_t)row * D_DIM + tid * 4;
    hr[0] = f2b((v.x - mean) * rstd);
    hr[1] = f2b((v.y - mean) * rstd);
    hr[2] = f2b((v.z - mean) * rstd);
    hr[3] = f2b((v.w - mean) * rstd);
}

// ---------------- exp(pos_bias) f32 -> bf16 ----------------
__global__ __launch_bounds__(256) void expw_kernel(const float* __restrict__ p,
                                                   bf16* __restrict__ w, int n4) {
    const int i = blockIdx.x * 256 + threadIdx.x;
    if (i < n4) {
        const float4 v = ((const float4*)p)[i];
        bf16* o = w + (size_t)i * 4;
        o[0] = f2b(expf(v.x)); o[1] = f2b(expf(v.y));
        o[2] = f2b(expf(v.z)); o[3] = f2b(expf(v.w));
    }
}

// ---------------- f32 -> bf16 convert ----------------
__global__ __launch_bounds__(256) void cvt_kernel(const float* __restrict__ p,
                                                  bf16* __restrict__ w, int n4) {
    const int i = blockIdx.x * 256 + threadIdx.x;
    if (i < n4) {
        const float4 v = ((const float4*)p)[i];
        bf16* o = w + (size_t)i * 4;
        o[0] = f2b(v.x); o[1] = f2b(v.y); o[2] = f2b(v.z); o[3] = f2b(v.w);
    }
}

// ---------------- transpose [2048,8192] -> [8192,2048]; EKVt = ek*v ----------------
__global__ __launch_bounds__(256) void transpose_ekv(
        const unsigned short* __restrict__ ek, const unsigned short* __restrict__ vv,
        unsigned short* __restrict__ EKt, unsigned short* __restrict__ EKVt) {
    __shared__ unsigned short le[64][68];
    __shared__ unsigned short lv[64][68];
    const int t0 = blockIdx.y * 64;   // over T=2048
    const int n0 = blockIdx.x * 64;   // over 8192
    const int tid = threadIdx.x;
    const int r = tid >> 4;           // 0..15
    const int c = tid & 15;           // 0..15
    #pragma unroll
    for (int rr = 0; rr < 4; rr++) {
        const int row = rr * 16 + r;  // t-local
        const size_t gi = (size_t)(t0 + row) * N8 + n0 + c * 4;
        const ushort4v e = *(const ushort4v*)(ek + gi);
        const ushort4v v = *(const ushort4v*)(vv + gi);
        *(ushort4v*)&le[row][c * 4] = e;
        *(ushort4v*)&lv[row][c * 4] = v;
    }
    __syncthreads();
    #pragma unroll
    for (int rr = 0; rr < 4; rr++) {
        const int nrow = rr * 16 + r; // n-local
        ushort4v eo, evo;
        #pragma unroll
        for (int j = 0; j < 4; j++) {
            const int tl = c * 4 + j;
            const unsigned short e = le[tl][nrow];
            const unsigned short v = lv[tl][nrow];
            eo[j]  = e;
            evo[j] = f2us(us2f(e) * us2f(v));
        }
        const size_t go = (size_t)(n0 + nrow) * T_DIM + t0 + c * 4;
        *(ushort4v*)(EKt + go)  = eo;
        *(ushort4v*)(EKVt + go) = evo;
    }
}

// ---------------- GEMM, B^T form: C[m,n] = sum_k A[m,k]*Bt[n,k] ----------------
// 128x128 tile, BK=32, 4 waves (2x2 of 64x64), mfma_f32_16x16x32_bf16.
enum { EPI_QKV = 0, EPI_BIAS_F32 = 1, EPI_FC2SUM = 2 };

template <int M, int N, int K, int EPI>
__global__ __launch_bounds__(256, 1)
void gemm_bt(const bf16* __restrict__ A, const bf16* __restrict__ Bt,
             const float* __restrict__ bias,
             void* __restrict__ o0, void* __restrict__ o1, void* __restrict__ o2,
             const float* __restrict__ e1, const float* __restrict__ e2) {
    constexpr int BK = 32;
    __shared__ bf16 As[128 * BK];
    __shared__ bf16 Bs[128 * BK];
    const int tid = threadIdx.x;
    const int lane = tid & 63;
    const int wv = tid >> 6;
    const int wm = wv >> 1, wn = wv & 1;
    const int m0 = blockIdx.y * 128, n0 = blockIdx.x * 128;

    const int sr = tid >> 2;           // staging row 0..63
    const int sc = (tid & 3) * 8;      // staging col
    const bf16* gA = A  + (size_t)(m0 + sr) * K + sc;
    const bf16* gB = Bt + (size_t)(n0 + sr) * K + sc;
    bf16* lA0 = As + tid * 8;
    bf16* lA1 = As + 2048 + tid * 8;
    bf16* lB0 = Bs + tid * 8;
    bf16* lB1 = Bs + 2048 + tid * 8;
    const size_t gstep = (size_t)64 * K;

    f32x4 acc[4][4];
    #pragma unroll
    for (int i = 0; i < 4; i++)
        #pragma unroll
        for (int j = 0; j < 4; j++) acc[i][j] = (f32x4){0.f, 0.f, 0.f, 0.f};

    const int lr = lane & 15;
    const int lk = (lane >> 4) * 8;

    for (int kt = 0; kt < K; kt += BK) {
        __syncthreads();
        gload_lds16(gA + kt, lA0);
        gload_lds16(gA + kt + gstep, lA1);
        gload_lds16(gB + kt, lB0);
        gload_lds16(gB + kt + gstep, lB1);
        asm volatile("s_waitcnt vmcnt(0)");
        __syncthreads();
        short8 a[4], b[4];
        #pragma unroll
        for (int i = 0; i < 4; i++)
            a[i] = *(const short8*)&As[(wm * 64 + i * 16 + lr) * BK + lk];
        #pragma unroll
        for (int i = 0; i < 4; i++)
            b[i] = *(const short8*)&Bs[(wn * 64 + i * 16 + lr) * BK + lk];
        #pragma unroll
        for (int i = 0; i < 4; i++)
            #pragma unroll
            for (int j = 0; j < 4; j++)
                acc[i][j] = __builtin_amdgcn_mfma_f32_16x16x32_bf16(a[i], b[j], acc[i][j], 0, 0, 0);
    }

    const int rbase = (lane >> 4) * 4;
    #pragma unroll
    for (int i = 0; i < 4; i++) {
        #pragma unroll
        for (int j = 0; j < 4; j++) {
            const int col = n0 + wn * 64 + j * 16 + lr;
            const float bv = bias[col];
            #pragma unroll
            for (int r = 0; r < 4; r++) {
                const int row = m0 + wm * 64 + i * 16 + rbase + r;
                const float c = acc[i][j][r] + bv;
                if constexpr (EPI == EPI_QKV) {
                    const int seg = col >> 10;       // 0:q 1:k 2:v (uniform per block)
                    const int nn = col & 1023;
                    const size_t idx = (size_t)row * 1024 + nn;
                    if (seg == 0)      ((bf16*)o0)[idx] = f2b(1.f / (1.f + expf(-c)));
                    else if (seg == 1) ((bf16*)o1)[idx] = f2b(expf(c));
                    else               ((bf16*)o2)[idx] = f2b(c);
                } else if constexpr (EPI == EPI_BIAS_F32) {
                    ((float*)o0)[(size_t)row * N + col] = c;
                } else { // EPI_FC2SUM
                    const size_t idx = (size_t)row * N + col;
                    ((float*)o0)[idx] = c + e1[idx] + e2[idx];
                }
            }
        }
    }
}

// ---------------- Twin-B GEMM: two accumulators sharing the A tile ----------------
enum { TEPI_ATTN = 0, TEPI_GLU = 1 };

template <int M, int N, int K, int EPI>
__global__ __launch_bounds__(256, 1)
void gemm_bt2(const bf16* __restrict__ A,
              const bf16* __restrict__ B1t, const bf16* __restrict__ B2t,
              const float* __restrict__ bias1, const float* __restrict__ bias2,
              const bf16* __restrict__ xin, bf16* __restrict__ out) {
    constexpr int BK = 32;
    __shared__ bf16 As[128 * BK];
    __shared__ bf16 B1s[128 * BK];
    __shared__ bf16 B2s[128 * BK];
    const int tid = threadIdx.x;
    const int lane = tid & 63;
    const int wv = tid >> 6;
    const int wm = wv >> 1, wn = wv & 1;
    const int m0 = blockIdx.y * 128, n0 = blockIdx.x * 128;

    const int sr = tid >> 2;
    const int sc = (tid & 3) * 8;
    const bf16* gA  = A   + (size_t)(m0 + sr) * K + sc;
    const bf16* gB1 = B1t + (size_t)(n0 + sr) * K + sc;
    const bf16* gB2 = B2t + (size_t)(n0 + sr) * K + sc;
    const size_t gstep = (size_t)64 * K;

    f32x4 acc1[4][4], acc2[4][4];
    #pragma unroll
    for (int i = 0; i < 4; i++)
        #pragma unroll
        for (int j = 0; j < 4; j++) {
            acc1[i][j] = (f32x4){0.f, 0.f, 0.f, 0.f};
            acc2[i][j] = (f32x4){0.f, 0.f, 0.f, 0.f};
        }

    const int lr = lane & 15;
    const int lk = (lane >> 4) * 8;

    for (int kt = 0; kt < K; kt += BK) {
        __syncthreads();
        gload_lds16(gA + kt,          As + tid * 8);
        gload_lds16(gA + kt + gstep,  As + 2048 + tid * 8);
        gload_lds16(gB1 + kt,         B1s + tid * 8);
        gload_lds16(gB1 + kt + gstep, B1s + 2048 + tid * 8);
        gload_lds16(gB2 + kt,         B2s + tid * 8);
        gload_lds16(gB2 + kt + gstep, B2s + 2048 + tid * 8);
        asm volatile("s_waitcnt vmcnt(0)");
        __syncthreads();
        short8 a[4], b1[4], b2[4];
        #pragma unroll
        for (int i = 0; i < 4; i++) {
            a[i]  = *(const short8*)&As [(wm * 64 + i * 16 + lr) * BK + lk];
            b1[i] = *(const short8*)&B1s[(wn * 64 + i * 16 + lr) * BK + lk];
            b2[i] = *(const short8*)&B2s[(wn * 64 + i * 16 + lr) * BK + lk];
        }
        #pragma unroll
        for (int i = 0; i < 4; i++)
            #pragma unroll
            for (int j = 0; j < 4; j++) {
                acc1[i][j] = __builtin_amdgcn_mfma_f32_16x16x32_bf16(a[i], b1[j], acc1[i][j], 0, 0, 0);
                acc2[i][j] = __builtin_amdgcn_mfma_f32_16x16x32_bf16(a[i], b2[j], acc2[i][j], 0, 0, 0);
            }
    }

    const int rbase = (lane >> 4) * 4;
    #pragma unroll
    for (int i = 0; i < 4; i++) {
        #pragma unroll
        for (int j = 0; j < 4; j++) {
            const int col = n0 + wn * 64 + j * 16 + lr;
            #pragma unroll
            for (int r = 0; r < 4; r++) {
                const int row = m0 + wm * 64 + i * 16 + rbase + r;
                const size_t idx = (size_t)row * N + col;
                if constexpr (EPI == TEPI_ATTN) {
                    const float num = acc1[i][j][r];
                    const float den = acc2[i][j][r];
                    const float s = b2f(xin[idx]);
                    out[idx] = f2b(s * (num / den));
                } else { // TEPI_GLU
                    const float x1 = acc1[i][j][r] + bias1[col];
                    const float g  = acc2[i][j][r] + bias2[col];
                    const float sp = (g > 20.f) ? g : log1pf(expf(g));
                    out[idx] = f2b(x1 * (g * tanhf(sp)));
                }
            }
        }
    }
}

// ---------------- launch ----------------
extern "C" void kernel_launch(void* const* d_in, const int* in_sizes, int n_in,
                              void* d_out, int out_size, void* d_ws, size_t ws_size,
                              hipStream_t stream) {
    const float* data  = (const float*)d_in[0];
    const float* qkv_w = (const float*)d_in[1];
    const float* qkv_b = (const float*)d_in[2];
    const float* pos_b = (const float*)d_in[3];
    const float* out_w = (const float*)d_in[4];
    const float* out_b = (const float*)d_in[5];
    const float* fc1_w = (const float*)d_in[6];
    const float* fc1_b = (const float*)d_in[7];
    const float* fc2_w = (const float*)d_in[8];
    const float* fc2_b = (const float*)d_in[9];
    float* out = (float*)d_out;

    char* ws = (char*)d_ws;
    const size_t SZ = (size_t)MROWS * D_DIM * 2;    // 33,554,432 B (bf16 [16384,1024])
    bf16* h      = (bf16*)(ws);
    bf16* Wb     = (bf16*)(ws + SZ);                       // exp(pos_bias) bf16 [2048,2048]
    bf16* sq     = (bf16*)(ws + SZ + 8388608);
    bf16* ek     = (bf16*)((char*)sq + SZ);
    bf16* vv     = (bf16*)((char*)ek + SZ);
    bf16* EKt    = (bf16*)((char*)vv + SZ);
    bf16* EKVt   = (bf16*)((char*)EKt + SZ);
    bf16* qkvw_b = (bf16*)((char*)EKVt + SZ);
    bf16* outw_b = qkvw_b + (size_t)3072 * 1024;
    bf16* fc1w_b = outw_b + (size_t)1024 * 1024;
    bf16* fc2w_b = fc1w_b + (size_t)2048 * 1024;
    // aliases (lifetimes disjoint):
    bf16*  Y    = ek;           // attn output (pre out-proj)
    float* aft  = (float*)EKt;  // f32 [16384,1024] spans EKt+EKVt
    bf16*  ffin = sq;           // x1*mish(gate)

    ln_kernel<<<MROWS, 256, 0, stream>>>(data, h);
    expw_kernel<<<4096, 256, 0, stream>>>(pos_b, Wb, T_DIM * T_DIM / 4);
    cvt_kernel<<<3072, 256, 0, stream>>>(qkv_w, qkvw_b, 3072 * 1024 / 4);
    cvt_kernel<<<1024, 256, 0, stream>>>(out_w, outw_b, 1024 * 1024 / 4);
    cvt_kernel<<<2048, 256, 0, stream>>>(fc1_w, fc1w_b, 2048 * 1024 / 4);
    cvt_kernel<<<1024, 256, 0, stream>>>(fc2_w, fc2w_b, 1024 * 1024 / 4);

    // QKV projection -> sigmoid(q), exp(k), v
    gemm_bt<MROWS, 3072, 1024, EPI_QKV><<<dim3(24, 128), 256, 0, stream>>>(
        h, qkvw_b, qkv_b, sq, ek, vv, nullptr, nullptr);

    // ek, ek*v transposed to [8192,2048]
    transpose_ekv<<<dim3(128, 32), 256, 0, stream>>>(
        (const unsigned short*)ek, (const unsigned short*)vv,
        (unsigned short*)EKt, (unsigned short*)EKVt);

    // num/den einsum + sigmoid(q)*(num/den), Y bf16 [2048,8192]
    gemm_bt2<T_DIM, N8, T_DIM, TEPI_ATTN><<<dim3(64, 16), 256, 0, stream>>>(
        Wb, EKVt, EKt, nullptr, nullptr, sq, Y);

    // out projection -> aft (f32)
    gemm_bt<MROWS, 1024, 1024, EPI_BIAS_F32><<<dim3(8, 128), 256, 0, stream>>>(
        Y, outw_b, out_b, aft, nullptr, nullptr, nullptr, nullptr);

    // fc1 twin + GLU -> ffin bf16
    gemm_bt2<MROWS, 1024, 1024, TEPI_GLU><<<dim3(8, 128), 256, 0, stream>>>(
        h, fc1w_b, fc1w_b + (size_t)1024 * 1024, fc1_b, fc1_b + 1024, nullptr, ffin);

    // fc2 + residual sum -> out (f32)
    gemm_bt<MROWS, 1024, 1024, EPI_FC2SUM><<<dim3(8, 128), 256, 0, stream>>>(
        ffin, fc2w_b, fc2_b, out, nullptr, nullptr, data, aft);
}

// Round 2
// 801.452 us; speedup vs baseline: 1.2452x; 1.2452x over previous
//
#include <hip/hip_runtime.h>
#include <hip/hip_bf16.h>
#include <cmath>
#include <cstdint>

using bf16 = __hip_bfloat16;
typedef __attribute__((ext_vector_type(8))) short short8;
typedef __attribute__((ext_vector_type(4))) float f32x4;
typedef __attribute__((ext_vector_type(4))) unsigned short ushort4v;

#define T_DIM 2048
#define B_DIM 8
#define D_DIM 1024
#define MROWS (T_DIM*B_DIM)   // 16384
#define N8 (B_DIM*D_DIM)      // 8192

__device__ __forceinline__ float b2f(bf16 x) { return __bfloat162float(x); }
__device__ __forceinline__ bf16  f2b(float x) { return __float2bfloat16(x); }
__device__ __forceinline__ float us2f(unsigned short u) {
    union { unsigned int i; float f; } x; x.i = ((unsigned int)u) << 16; return x.f;
}
__device__ __forceinline__ unsigned short f2us(float f) {
    bf16 b = __float2bfloat16(f);
    return *(unsigned short*)&b;
}

// async global->LDS, 16B per lane. LDS dest must be wave-uniform-base + lane*16.
__device__ __forceinline__ void gload_lds16(const bf16* g, bf16* l) {
    __builtin_amdgcn_global_load_lds(
        (const __attribute__((address_space(1))) unsigned int*)g,
        (__attribute__((address_space(3))) unsigned int*)l,
        16, 0, 0);
}

// ---------------- LayerNorm: f32 [16384,1024] -> bf16 ----------------
__global__ __launch_bounds__(256) void ln_kernel(const float* __restrict__ x,
                                                 bf16* __restrict__ h) {
    const int row = blockIdx.x;
    const int tid = threadIdx.x;
    const float4 v = ((const float4*)(x + (size_t)row * D_DIM))[tid];
    float s1 = v.x + v.y + v.z + v.w;
    float s2 = v.x*v.x + v.y*v.y + v.z*v.z + v.w*v.w;
    #pragma unroll
    for (int off = 32; off > 0; off >>= 1) {
        s1 += __shfl_down(s1, off);
        s2 += __shfl_down(s2, off);
    }
    __shared__ float red[8];
    const int lane = tid & 63, wv = tid >> 6;
    if (lane == 0) { red[wv*2] = s1; red[wv*2+1] = s2; }
    __syncthreads();
    s1 = red[0] + red[2] + red[4] + red[6];
    s2 = red[1] + red[3] + red[5] + red[7];
    const float mean = s1 * (1.0f / D_DIM);
    const float var  = s2 * (1.0f / D_DIM) - mean * mean;
    const float rstd = rsqrtf(var + 1.1754943508222875e-38f);
    bf16* hr = h + (size_t)row * D_DIM + tid * 4;
    hr[0] = f2b((v.x - mean) * rstd);
    hr[1] = f2b((v.y - mean) * rstd);
    hr[2] = f2b((v.z - mean) * rstd);
    hr[3] = f2b((v.w - mean) * rstd);
}

// ---------------- exp(pos_bias) f32 -> bf16 ----------------
__global__ __launch_bounds__(256) void expw_kernel(const float* __restrict__ p,
                                                   bf16* __restrict__ w, int n4) {
    const int i = blockIdx.x * 256 + threadIdx.x;
    if (i < n4) {
        const float4 v = ((const float4*)p)[i];
        bf16* o = w + (size_t)i * 4;
        o[0] = f2b(expf(v.x)); o[1] = f2b(expf(v.y));
        o[2] = f2b(expf(v.z)); o[3] = f2b(expf(v.w));
    }
}

// ---------------- f32 -> bf16 convert ----------------
__global__ __launch_bounds__(256) void cvt_kernel(const float* __restrict__ p,
                                                  bf16* __restrict__ w, int n4) {
    const int i = blockIdx.x * 256 + threadIdx.x;
    if (i < n4) {
        const float4 v = ((const float4*)p)[i];
        bf16* o = w + (size_t)i * 4;
        o[0] = f2b(v.x); o[1] = f2b(v.y); o[2] = f2b(v.z); o[3] = f2b(v.w);
    }
}

// ---------------- transpose [2048,8192] -> [8192,2048]; EKVt = ek*v ----------------
__global__ __launch_bounds__(256) void transpose_ekv(
        const unsigned short* __restrict__ ek, const unsigned short* __restrict__ vv,
        unsigned short* __restrict__ EKt, unsigned short* __restrict__ EKVt) {
    __shared__ unsigned short le[64][68];
    __shared__ unsigned short lv[64][68];
    const int t0 = blockIdx.y * 64;   // over T=2048
    const int n0 = blockIdx.x * 64;   // over 8192
    const int tid = threadIdx.x;
    const int r = tid >> 4;           // 0..15
    const int c = tid & 15;           // 0..15
    #pragma unroll
    for (int rr = 0; rr < 4; rr++) {
        const int row = rr * 16 + r;  // t-local
        const size_t gi = (size_t)(t0 + row) * N8 + n0 + c * 4;
        const ushort4v e = *(const ushort4v*)(ek + gi);
        const ushort4v v = *(const ushort4v*)(vv + gi);
        *(ushort4v*)&le[row][c * 4] = e;
        *(ushort4v*)&lv[row][c * 4] = v;
    }
    __syncthreads();
    #pragma unroll
    for (int rr = 0; rr < 4; rr++) {
        const int nrow = rr * 16 + r; // n-local
        ushort4v eo, evo;
        #pragma unroll
        for (int j = 0; j < 4; j++) {
            const int tl = c * 4 + j;
            const unsigned short e = le[tl][nrow];
            const unsigned short v = lv[tl][nrow];
            eo[j]  = e;
            evo[j] = f2us(us2f(e) * us2f(v));
        }
        const size_t go = (size_t)(n0 + nrow) * T_DIM + t0 + c * 4;
        *(ushort4v*)(EKt + go)  = eo;
        *(ushort4v*)(EKVt + go) = evo;
    }
}

// ---------------- attn combine: Y = sigmoid(q) * num/den ----------------
// Ccat [2048, 16384] bf16: cols 0..8191 = den, 8192..16383 = num.
__global__ __launch_bounds__(256) void attn_combine(
        const unsigned short* __restrict__ C, const unsigned short* __restrict__ sq,
        unsigned short* __restrict__ Y) {
    const size_t i8 = (size_t)blockIdx.x * 256 + threadIdx.x;
    const size_t j0 = i8 * 8;                 // flat over [2048, 8192]
    const int t = (int)(j0 >> 13);
    const int u = (int)(j0 & 8191);
    const size_t cbase = (size_t)t * 16384 + u;
    const short8 den = *(const short8*)(C + cbase);
    const short8 num = *(const short8*)(C + cbase + 8192);
    const short8 s   = *(const short8*)(sq + j0);
    short8 y;
    #pragma unroll
    for (int j = 0; j < 8; j++) {
        const float n = us2f((unsigned short)num[j]);
        const float d = us2f((unsigned short)den[j]);
        const float sv = us2f((unsigned short)s[j]);
        y[j] = (short)f2us(sv * (n / d));
    }
    *(short8*)(Y + j0) = y;
}

// ---------------- GLU combine: ffin = x1 * mish(gate) ----------------
// x12 [16384, 2048] bf16: cols 0..1023 = x1, 1024..2047 = gate.
__global__ __launch_bounds__(256) void glu_combine(
        const unsigned short* __restrict__ x12, unsigned short* __restrict__ ffin) {
    const size_t i8 = (size_t)blockIdx.x * 256 + threadIdx.x;
    const size_t j0 = i8 * 8;                 // flat over [16384, 1024]
    const int row = (int)(j0 >> 10);
    const int d = (int)(j0 & 1023);
    const size_t base = (size_t)row * 2048 + d;
    const short8 x1v = *(const short8*)(x12 + base);
    const short8 gv  = *(const short8*)(x12 + base + 1024);
    short8 o;
    #pragma unroll
    for (int j = 0; j < 8; j++) {
        const float x1 = us2f((unsigned short)x1v[j]);
        const float g  = us2f((unsigned short)gv[j]);
        const float sp = (g > 20.f) ? g : log1pf(expf(g));
        o[j] = (short)f2us(x1 * (g * tanhf(sp)));
    }
    *(short8*)(ffin + j0) = o;
}

// ---------------- GEMM, B^T form: C[m,n] = sum_k A[m,k]*Bt[n,k] ----------------
// 128x128 tile, BK=32, 4 waves (2x2 of 64x64), mfma_f32_16x16x32_bf16.
enum { EPI_QKV = 0, EPI_BIAS_F32 = 1, EPI_FC2SUM = 2, EPI_STORE_BF16 = 3, EPI_BIAS_BF16 = 4 };

template <int M, int N, int K, int EPI>
__global__ __launch_bounds__(256, 1)
void gemm_bt(const bf16* __restrict__ A, const bf16* __restrict__ Bt,
             const float* __restrict__ bias,
             void* __restrict__ o0, void* __restrict__ o1, void* __restrict__ o2,
             const float* __restrict__ e1, const float* __restrict__ e2) {
    constexpr int BK = 32;
    __shared__ bf16 As[128 * BK];
    __shared__ bf16 Bs[128 * BK];
    const int tid = threadIdx.x;
    const int lane = tid & 63;
    const int wv = tid >> 6;
    const int wm = wv >> 1, wn = wv & 1;
    const int m0 = blockIdx.y * 128, n0 = blockIdx.x * 128;

    const int sr = tid >> 2;           // staging row 0..63
    const int sc = (tid & 3) * 8;      // staging col
    const bf16* gA = A  + (size_t)(m0 + sr) * K + sc;
    const bf16* gB = Bt + (size_t)(n0 + sr) * K + sc;
    bf16* lA0 = As + tid * 8;
    bf16* lA1 = As + 2048 + tid * 8;
    bf16* lB0 = Bs + tid * 8;
    bf16* lB1 = Bs + 2048 + tid * 8;
    const size_t gstep = (size_t)64 * K;

    f32x4 acc[4][4];
    #pragma unroll
    for (int i = 0; i < 4; i++)
        #pragma unroll
        for (int j = 0; j < 4; j++) acc[i][j] = (f32x4){0.f, 0.f, 0.f, 0.f};

    const int lr = lane & 15;
    const int lk = (lane >> 4) * 8;

    for (int kt = 0; kt < K; kt += BK) {
        __syncthreads();
        gload_lds16(gA + kt, lA0);
        gload_lds16(gA + kt + gstep, lA1);
        gload_lds16(gB + kt, lB0);
        gload_lds16(gB + kt + gstep, lB1);
        asm volatile("s_waitcnt vmcnt(0)");
        __syncthreads();
        short8 a[4], b[4];
        #pragma unroll
        for (int i = 0; i < 4; i++)
            a[i] = *(const short8*)&As[(wm * 64 + i * 16 + lr) * BK + lk];
        #pragma unroll
        for (int i = 0; i < 4; i++)
            b[i] = *(const short8*)&Bs[(wn * 64 + i * 16 + lr) * BK + lk];
        #pragma unroll
        for (int i = 0; i < 4; i++)
            #pragma unroll
            for (int j = 0; j < 4; j++)
                acc[i][j] = __builtin_amdgcn_mfma_f32_16x16x32_bf16(a[i], b[j], acc[i][j], 0, 0, 0);
    }

    const int rbase = (lane >> 4) * 4;
    #pragma unroll
    for (int i = 0; i < 4; i++) {
        #pragma unroll
        for (int j = 0; j < 4; j++) {
            const int col = n0 + wn * 64 + j * 16 + lr;
            float bv = 0.f;
            if constexpr (EPI != EPI_STORE_BF16) bv = bias[col];
            #pragma unroll
            for (int r = 0; r < 4; r++) {
                const int row = m0 + wm * 64 + i * 16 + rbase + r;
                const float c = acc[i][j][r] + bv;
                if constexpr (EPI == EPI_QKV) {
                    const int seg = col >> 10;       // 0:q 1:k 2:v (uniform per block)
                    const int nn = col & 1023;
                    const size_t idx = (size_t)row * 1024 + nn;
                    if (seg == 0)      ((bf16*)o0)[idx] = f2b(1.f / (1.f + expf(-c)));
                    else if (seg == 1) ((bf16*)o1)[idx] = f2b(expf(c));
                    else               ((bf16*)o2)[idx] = f2b(c);
                } else if constexpr (EPI == EPI_BIAS_F32) {
                    ((float*)o0)[(size_t)row * N + col] = c;
                } else if constexpr (EPI == EPI_STORE_BF16 || EPI == EPI_BIAS_BF16) {
                    ((bf16*)o0)[(size_t)row * N + col] = f2b(c);
                } else { // EPI_FC2SUM
                    const size_t idx = (size_t)row * N + col;
                    ((float*)o0)[idx] = c + e1[idx] + e2[idx];
                }
            }
        }
    }
}

// ---------------- launch ----------------
extern "C" void kernel_launch(void* const* d_in, const int* in_sizes, int n_in,
                              void* d_out, int out_size, void* d_ws, size_t ws_size,
                              hipStream_t stream) {
    const float* data  = (const float*)d_in[0];
    const float* qkv_w = (const float*)d_in[1];
    const float* qkv_b = (const float*)d_in[2];
    const float* pos_b = (const float*)d_in[3];
    const float* out_w = (const float*)d_in[4];
    const float* out_b = (const float*)d_in[5];
    const float* fc1_w = (const float*)d_in[6];
    const float* fc1_b = (const float*)d_in[7];
    const float* fc2_w = (const float*)d_in[8];
    const float* fc2_b = (const float*)d_in[9];
    float* out = (float*)d_out;

    char* ws = (char*)d_ws;
    const size_t MB = 1024ull * 1024ull;
    // Time-shared layout (max 214 MB):
    bf16* h    = (bf16*)(ws);              // 0..32MB      LN(data), live until fc1
    bf16* Wb   = (bf16*)(ws + 32*MB);      // 32..40MB     exp(pos_bias)
    bf16* sq   = (bf16*)(ws + 40*MB);      // 40..72MB     sigmoid(q), live until combine
    char* slotA = ws + 72*MB;              // 72..136MB    ek|vv -> Ccat -> x12
    char* slotB = ws + 136*MB;             // 136..200MB   EKt|EKVt -> Y|ffin
    bf16* qkvw_b = (bf16*)(ws + 200*MB);   // 6MB
    bf16* outw_b = qkvw_b + (size_t)3072 * 1024;  // 2MB
    bf16* fc1w_b = outw_b + (size_t)1024 * 1024;  // 4MB
    bf16* fc2w_b = fc1w_b + (size_t)2048 * 1024;  // 2MB -> ends at 214MB

    bf16* ek   = (bf16*)slotA;             // [2048, 8192]
    bf16* vv   = (bf16*)(slotA + 32*MB);
    bf16* EKt  = (bf16*)slotB;             // [8192, 2048] (den B), then num B adjacent
    bf16* EKVt = (bf16*)(slotB + 32*MB);
    bf16* Ccat = (bf16*)slotA;             // [2048, 16384] bf16
    bf16* Y    = (bf16*)slotB;             // [2048, 8192]  (overwrites EKt after attn gemm)
    bf16* x12  = (bf16*)slotA;             // [16384, 2048] (overwrites Ccat after combine)
    bf16* ffin = (bf16*)(slotB + 32*MB);   // [16384, 1024] (overwrites EKVt)

    ln_kernel<<<MROWS, 256, 0, stream>>>(data, h);
    expw_kernel<<<4096, 256, 0, stream>>>(pos_b, Wb, T_DIM * T_DIM / 4);
    cvt_kernel<<<3072, 256, 0, stream>>>(qkv_w, qkvw_b, 3072 * 1024 / 4);
    cvt_kernel<<<1024, 256, 0, stream>>>(out_w, outw_b, 1024 * 1024 / 4);
    cvt_kernel<<<2048, 256, 0, stream>>>(fc1_w, fc1w_b, 2048 * 1024 / 4);
    cvt_kernel<<<1024, 256, 0, stream>>>(fc2_w, fc2w_b, 1024 * 1024 / 4);

    // QKV projection -> sigmoid(q), exp(k), v
    gemm_bt<MROWS, 3072, 1024, EPI_QKV><<<dim3(24, 128), 256, 0, stream>>>(
        h, qkvw_b, qkv_b, sq, ek, vv, nullptr, nullptr);

    // ek, ek*v transposed to [8192,2048] (EKt then EKVt = Bcat rows 0..16383)
    transpose_ekv<<<dim3(128, 32), 256, 0, stream>>>(
        (const unsigned short*)ek, (const unsigned short*)vv,
        (unsigned short*)EKt, (unsigned short*)EKVt);

    // one big GEMM: Ccat[t, 0..8191]=den, [8192..16383]=num
    gemm_bt<T_DIM, 2 * N8, T_DIM, EPI_STORE_BF16><<<dim3(128, 16), 256, 0, stream>>>(
        Wb, EKt, nullptr, Ccat, nullptr, nullptr, nullptr, nullptr);

    // Y = sigmoid(q) * num/den
    attn_combine<<<8192, 256, 0, stream>>>(
        (const unsigned short*)Ccat, (const unsigned short*)sq, (unsigned short*)Y);

    // out projection -> aft stored in d_out (f32)
    gemm_bt<MROWS, 1024, 1024, EPI_BIAS_F32><<<dim3(8, 128), 256, 0, stream>>>(
        Y, outw_b, out_b, out, nullptr, nullptr, nullptr, nullptr);

    // fc1 (both halves) -> x12 bf16 [16384, 2048]
    gemm_bt<MROWS, 2048, 1024, EPI_BIAS_BF16><<<dim3(16, 128), 256, 0, stream>>>(
        h, fc1w_b, fc1_b, x12, nullptr, nullptr, nullptr, nullptr);

    // ffin = x1 * mish(gate)
    glu_combine<<<8192, 256, 0, stream>>>(
        (const unsigned short*)x12, (unsigned short*)ffin);

    // fc2 + residual: out = c + data + aft(d_out)
    gemm_bt<MROWS, 1024, 1024, EPI_FC2SUM><<<dim3(8, 128), 256, 0, stream>>>(
        ffin, fc2w_b, fc2_b, out, nullptr, nullptr, data, out);
}

// Round 3
// 728.503 us; speedup vs baseline: 1.3698x; 1.1001x over previous
//
#include <hip/hip_runtime.h>
#include <hip/hip_bf16.h>
#include <cmath>
#include <cstdint>

using bf16 = __hip_bfloat16;
typedef __attribute__((ext_vector_type(8))) short short8;
typedef __attribute__((ext_vector_type(4))) float f32x4;
typedef __attribute__((ext_vector_type(4))) unsigned short ushort4v;

#define T_DIM 2048
#define B_DIM 8
#define D_DIM 1024
#define MROWS (T_DIM*B_DIM)   // 16384
#define N8 (B_DIM*D_DIM)      // 8192

__device__ __forceinline__ float b2f(bf16 x) { return __bfloat162float(x); }
__device__ __forceinline__ bf16  f2b(float x) { return __float2bfloat16(x); }
__device__ __forceinline__ float us2f(unsigned short u) {
    union { unsigned int i; float f; } x; x.i = ((unsigned int)u) << 16; return x.f;
}
__device__ __forceinline__ unsigned short f2us(float f) {
    bf16 b = __float2bfloat16(f);
    return *(unsigned short*)&b;
}

// async global->LDS, 16B per lane. LDS dest must be wave-uniform base + lane*16.
__device__ __forceinline__ void gload_lds16(const bf16* g, char* l) {
    __builtin_amdgcn_global_load_lds(
        (const __attribute__((address_space(1))) unsigned int*)g,
        (__attribute__((address_space(3))) unsigned int*)l,
        16, 0, 0);
}

// ---------------- LayerNorm: f32 [16384,1024] -> bf16 ----------------
__global__ __launch_bounds__(256) void ln_kernel(const float* __restrict__ x,
                                                 bf16* __restrict__ h) {
    const int row = blockIdx.x;
    const int tid = threadIdx.x;
    const float4 v = ((const float4*)(x + (size_t)row * D_DIM))[tid];
    float s1 = v.x + v.y + v.z + v.w;
    float s2 = v.x*v.x + v.y*v.y + v.z*v.z + v.w*v.w;
    #pragma unroll
    for (int off = 32; off > 0; off >>= 1) {
        s1 += __shfl_down(s1, off);
        s2 += __shfl_down(s2, off);
    }
    __shared__ float red[8];
    const int lane = tid & 63, wv = tid >> 6;
    if (lane == 0) { red[wv*2] = s1; red[wv*2+1] = s2; }
    __syncthreads();
    s1 = red[0] + red[2] + red[4] + red[6];
    s2 = red[1] + red[3] + red[5] + red[7];
    const float mean = s1 * (1.0f / D_DIM);
    const float var  = s2 * (1.0f / D_DIM) - mean * mean;
    const float rstd = rsqrtf(var + 1.1754943508222875e-38f);
    bf16* hr = h + (size_t)row * D_DIM + tid * 4;
    hr[0] = f2b((v.x - mean) * rstd);
    hr[1] = f2b((v.y - mean) * rstd);
    hr[2] = f2b((v.z - mean) * rstd);
    hr[3] = f2b((v.w - mean) * rstd);
}

// ---------------- exp(pos_bias) f32 -> bf16 ----------------
__global__ __launch_bounds__(256) void expw_kernel(const float* __restrict__ p,
                                                   bf16* __restrict__ w, int n4) {
    const int i = blockIdx.x * 256 + threadIdx.x;
    if (i < n4) {
        const float4 v = ((const float4*)p)[i];
        bf16* o = w + (size_t)i * 4;
        o[0] = f2b(expf(v.x)); o[1] = f2b(expf(v.y));
        o[2] = f2b(expf(v.z)); o[3] = f2b(expf(v.w));
    }
}

// ---------------- f32 -> bf16 convert ----------------
__global__ __launch_bounds__(256) void cvt_kernel(const float* __restrict__ p,
                                                  bf16* __restrict__ w, int n4) {
    const int i = blockIdx.x * 256 + threadIdx.x;
    if (i < n4) {
        const float4 v = ((const float4*)p)[i];
        bf16* o = w + (size_t)i * 4;
        o[0] = f2b(v.x); o[1] = f2b(v.y); o[2] = f2b(v.z); o[3] = f2b(v.w);
    }
}

// ---------------- transpose [2048,8192] -> [8192,2048]; EKVt = ek*v ----------------
__global__ __launch_bounds__(256) void transpose_ekv(
        const unsigned short* __restrict__ ek, const unsigned short* __restrict__ vv,
        unsigned short* __restrict__ EKt, unsigned short* __restrict__ EKVt) {
    __shared__ unsigned short le[64][68];
    __shared__ unsigned short lv[64][68];
    const int t0 = blockIdx.y * 64;
    const int n0 = blockIdx.x * 64;
    const int tid = threadIdx.x;
    const int r = tid >> 4;
    const int c = tid & 15;
    #pragma unroll
    for (int rr = 0; rr < 4; rr++) {
        const int row = rr * 16 + r;
        const size_t gi = (size_t)(t0 + row) * N8 + n0 + c * 4;
        const ushort4v e = *(const ushort4v*)(ek + gi);
        const ushort4v v = *(const ushort4v*)(vv + gi);
        *(ushort4v*)&le[row][c * 4] = e;
        *(ushort4v*)&lv[row][c * 4] = v;
    }
    __syncthreads();
    #pragma unroll
    for (int rr = 0; rr < 4; rr++) {
        const int nrow = rr * 16 + r;
        ushort4v eo, evo;
        #pragma unroll
        for (int j = 0; j < 4; j++) {
            const int tl = c * 4 + j;
            const unsigned short e = le[tl][nrow];
            const unsigned short v = lv[tl][nrow];
            eo[j]  = e;
            evo[j] = f2us(us2f(e) * us2f(v));
        }
        const size_t go = (size_t)(n0 + nrow) * T_DIM + t0 + c * 4;
        *(ushort4v*)(EKt + go)  = eo;
        *(ushort4v*)(EKVt + go) = evo;
    }
}

// ---------------- attn combine: Y = sigmoid(q) * num/den ----------------
__global__ __launch_bounds__(256) void attn_combine(
        const unsigned short* __restrict__ C, const unsigned short* __restrict__ sq,
        unsigned short* __restrict__ Y) {
    const size_t i8 = (size_t)blockIdx.x * 256 + threadIdx.x;
    const size_t j0 = i8 * 8;
    const int t = (int)(j0 >> 13);
    const int u = (int)(j0 & 8191);
    const size_t cbase = (size_t)t * 16384 + u;
    const short8 den = *(const short8*)(C + cbase);
    const short8 num = *(const short8*)(C + cbase + 8192);
    const short8 s   = *(const short8*)(sq + j0);
    short8 y;
    #pragma unroll
    for (int j = 0; j < 8; j++) {
        const float n = us2f((unsigned short)num[j]);
        const float d = us2f((unsigned short)den[j]);
        const float sv = us2f((unsigned short)s[j]);
        y[j] = (short)f2us(sv * (n / d));
    }
    *(short8*)(Y + j0) = y;
}

// ---------------- GLU combine: ffin = x1 * mish(gate) ----------------
__global__ __launch_bounds__(256) void glu_combine(
        const unsigned short* __restrict__ x12, unsigned short* __restrict__ ffin) {
    const size_t i8 = (size_t)blockIdx.x * 256 + threadIdx.x;
    const size_t j0 = i8 * 8;
    const int row = (int)(j0 >> 10);
    const int d = (int)(j0 & 1023);
    const size_t base = (size_t)row * 2048 + d;
    const short8 x1v = *(const short8*)(x12 + base);
    const short8 gv  = *(const short8*)(x12 + base + 1024);
    short8 o;
    #pragma unroll
    for (int j = 0; j < 8; j++) {
        const float x1 = us2f((unsigned short)x1v[j]);
        const float g  = us2f((unsigned short)gv[j]);
        const float sp = (g > 20.f) ? g : log1pf(expf(g));
        o[j] = (short)f2us(x1 * (g * tanhf(sp)));
    }
    *(short8*)(ffin + j0) = o;
}

// ================= 256x256 8-phase GEMM (T2+T3+T4+T5+T1) ====================
// C[m,n] = sum_k A[m,k]*Bt[n,k].  512 thr = 8 waves (2x4), BK=64, 2 K-tiles/iter.
// LDS 128KB: buf{0,1} x { A0,A1,B0,B1 } halves of 16KB ([128 rows][64 cols] bf16).
// st_16x32 swizzle: byte ^= ((byte>>9)&1)<<5 ; linear LDS dest (global_load_lds),
// pre-swizzled global source, swizzled ds_read address (involution both sides).
enum { EPI_QKV = 0, EPI_BIAS_F32 = 1, EPI_FC2SUM = 2, EPI_STORE_BF16 = 3, EPI_BIAS_BF16 = 4 };

#define BAR() __builtin_amdgcn_s_barrier()

#define RD_A(ABASE, MOFF)                                                     \
    _Pragma("unroll")                                                         \
    for (int m = 0; m < 4; m++) {                                             \
        a[m][0] = *(const short8*)(lds + (ABASE) + (MOFF + m) * 2048 + ck0);  \
        a[m][1] = *(const short8*)(lds + (ABASE) + (MOFF + m) * 2048 + ck1);  \
    }

#define RD_B(BBASE, NOFF, BREG)                                               \
    _Pragma("unroll")                                                         \
    for (int n = 0; n < 2; n++) {                                             \
        BREG[n][0] = *(const short8*)(lds + (BBASE) + (NOFF + n) * 2048 + ck0);\
        BREG[n][1] = *(const short8*)(lds + (BBASE) + (NOFF + n) * 2048 + ck1);\
    }

#define MFMA_QUAD(MB, NB, BREG)                                               \
    __builtin_amdgcn_s_setprio(1);                                            \
    _Pragma("unroll")                                                         \
    for (int m = 0; m < 4; m++) {                                             \
        _Pragma("unroll")                                                     \
        for (int n = 0; n < 2; n++) {                                         \
            acc[MB + m][NB + n] = __builtin_amdgcn_mfma_f32_16x16x32_bf16(    \
                a[m][0], BREG[n][0], acc[MB + m][NB + n], 0, 0, 0);           \
            acc[MB + m][NB + n] = __builtin_amdgcn_mfma_f32_16x16x32_bf16(    \
                a[m][1], BREG[n][1], acc[MB + m][NB + n], 0, 0, 0);           \
        }                                                                     \
    }                                                                         \
    __builtin_amdgcn_s_setprio(0);

template <int M, int N, int K, int EPI>
__global__ __launch_bounds__(512, 2)
void gemm8(const bf16* __restrict__ A, const bf16* __restrict__ Bt,
           const float* __restrict__ bias,
           void* __restrict__ o0, void* __restrict__ o1, void* __restrict__ o2,
           const float* __restrict__ e1, const float* __restrict__ e2) {
    constexpr int NK = K / 64;
    constexpr int NIT = NK / 2;
    constexpr int KMASK = NK - 1;
    __shared__ char lds[131072];
    const int tid = threadIdx.x;
    const int lane = tid & 63;
    const int wid = tid >> 6;
    const int wr = wid >> 2, wc = wid & 3;
    const int lr = lane & 15;

    // XCD-aware bijective swizzle (all grids are multiples of 8 blocks)
    const int nwg = gridDim.x * gridDim.y;
    int lin = blockIdx.y * gridDim.x + blockIdx.x;
    lin = (lin & 7) * (nwg >> 3) + (lin >> 3);
    const int bx = lin % gridDim.x, by = lin / gridDim.x;
    const int m0 = by * 256, n0 = bx * 256;

    // staging constants (source pre-swizzle)
    const int srow = tid >> 3;                                     // 0..63
    const int scol = ((tid & 7) * 8) ^ (((tid >> 5) & 1) << 4);    // elements
    const int sdst = tid * 16;                                     // bytes

    // read constants (read-side swizzle)
    const int cx  = ((lane >> 2) & 1) << 5;
    const int ck0 = (((lane >> 4) * 16)) ^ cx;
    const int ck1 = (64 + ((lane >> 4) * 16)) ^ cx;
    const int abase0 = wr * 16384 + lr * 128;
    const int abase1 = 65536 + abase0;
    const int bbase0 = 32768 + (wc >> 1) * 16384 + ((wc & 1) * 64 + lr) * 128;
    const int bbase1 = 65536 + bbase0;

    auto STAGE = [&](const bf16* P, int r0, int kt, int ldsoff) {
        gload_lds16(P + (size_t)(r0 + srow) * K + kt + scol, lds + ldsoff + sdst);
        gload_lds16(P + (size_t)(r0 + 64 + srow) * K + kt + scol,
                    lds + ldsoff + 8192 + sdst);
    };

    f32x4 acc[8][4] = {};
    short8 a[4][2], blo[2][2], bhi[2][2];

    // prologue: tile0 (all 4 halves) + B0(1), A0(1); leave last 2 halves in flight
    STAGE(A,  m0,       0, 0);
    STAGE(A,  m0 + 128, 0, 16384);
    STAGE(Bt, n0,       0, 32768);
    STAGE(Bt, n0 + 128, 0, 49152);
    STAGE(Bt, n0,      64, 65536 + 32768);
    STAGE(A,  m0,      64, 65536);
    asm volatile("s_waitcnt vmcnt(4)");
    BAR();

    for (int i = 0; i < NIT; ++i) {
        const int t1k = ((2 * i + 1) & KMASK) * 64;
        const int t2k = ((2 * i + 2) & KMASK) * 64;
        const int t3k = ((2 * i + 3) & KMASK) * 64;
        // p1: (mlo,nlo) of tile U(buf0); stage B1(V)
        RD_A(abase0, 0); RD_B(bbase0, 0, blo);
        STAGE(Bt, n0 + 128, t1k, 65536 + 49152);
        BAR(); MFMA_QUAD(0, 0, blo); BAR();
        // p2: (mlo,nhi); stage A1(V)
        RD_B(bbase0, 2, bhi);
        STAGE(A, m0 + 128, t1k, 65536 + 16384);
        BAR(); MFMA_QUAD(0, 2, bhi); BAR();
        // p3: (mhi,nhi); stage B0(t+2)
        RD_A(abase0, 4);
        STAGE(Bt, n0, t2k, 32768);
        BAR(); MFMA_QUAD(4, 2, bhi); BAR();
        // p4: (mhi,nlo); stage A0(t+2); counted wait -> tile V fully landed
        STAGE(A, m0, t2k, 0);
        asm volatile("s_waitcnt vmcnt(4)");
        BAR(); MFMA_QUAD(4, 0, blo); BAR();
        // p5: (mlo,nlo) of tile V(buf1); stage A1(t+2)
        RD_A(abase1, 0); RD_B(bbase1, 0, blo);
        STAGE(A, m0 + 128, t2k, 16384);
        BAR(); MFMA_QUAD(0, 0, blo); BAR();
        // p6: (mlo,nhi); stage B1(t+2)
        RD_B(bbase1, 2, bhi);
        STAGE(Bt, n0 + 128, t2k, 49152);
        BAR(); MFMA_QUAD(0, 2, bhi); BAR();
        // p7: (mhi,nhi); stage B0(t+3)
        RD_A(abase1, 4);
        STAGE(Bt, n0, t3k, 65536 + 32768);
        BAR(); MFMA_QUAD(4, 2, bhi); BAR();
        // p8: (mhi,nlo); stage A0(t+3); counted wait -> tile t+2 fully landed
        STAGE(A, m0, t3k, 65536);
        asm volatile("s_waitcnt vmcnt(4)");
        BAR(); MFMA_QUAD(4, 0, blo); BAR();
    }
    asm volatile("s_waitcnt vmcnt(0)");  // drain DMA before LDS teardown

    // epilogue
    const int rb = (lane >> 4) * 4;
    #pragma unroll
    for (int mm = 0; mm < 8; mm++) {
        #pragma unroll
        for (int nn = 0; nn < 4; nn++) {
            const int col = n0 + wc * 64 + nn * 16 + lr;
            float bv = 0.f;
            if constexpr (EPI != EPI_STORE_BF16) bv = bias[col];
            const int row0 = m0 + wr * 128 + mm * 16 + rb;
            #pragma unroll
            for (int r = 0; r < 4; r++) {
                const int row = row0 + r;
                const float c = acc[mm][nn][r] + bv;
                if constexpr (EPI == EPI_QKV) {
                    const int seg = col >> 10;
                    const int nc = col & 1023;
                    const size_t idx = (size_t)row * 1024 + nc;
                    if (seg == 0)      ((bf16*)o0)[idx] = f2b(1.f / (1.f + expf(-c)));
                    else if (seg == 1) ((bf16*)o1)[idx] = f2b(expf(c));
                    else               ((bf16*)o2)[idx] = f2b(c);
                } else if constexpr (EPI == EPI_BIAS_F32) {
                    ((float*)o0)[(size_t)row * N + col] = c;
                } else if constexpr (EPI == EPI_STORE_BF16 || EPI == EPI_BIAS_BF16) {
                    ((bf16*)o0)[(size_t)row * N + col] = f2b(c);
                } else { // EPI_FC2SUM
                    const size_t idx = (size_t)row * N + col;
                    ((float*)o0)[idx] = c + e1[idx] + e2[idx];
                }
            }
        }
    }
}

// ---------------- launch ----------------
extern "C" void kernel_launch(void* const* d_in, const int* in_sizes, int n_in,
                              void* d_out, int out_size, void* d_ws, size_t ws_size,
                              hipStream_t stream) {
    const float* data  = (const float*)d_in[0];
    const float* qkv_w = (const float*)d_in[1];
    const float* qkv_b = (const float*)d_in[2];
    const float* pos_b = (const float*)d_in[3];
    const float* out_w = (const float*)d_in[4];
    const float* out_b = (const float*)d_in[5];
    const float* fc1_w = (const float*)d_in[6];
    const float* fc1_b = (const float*)d_in[7];
    const float* fc2_w = (const float*)d_in[8];
    const float* fc2_b = (const float*)d_in[9];
    float* out = (float*)d_out;

    char* ws = (char*)d_ws;
    const size_t MB = 1024ull * 1024ull;
    bf16* h    = (bf16*)(ws);              // 0..32MB
    bf16* Wb   = (bf16*)(ws + 32*MB);      // 32..40MB
    bf16* sq   = (bf16*)(ws + 40*MB);      // 40..72MB
    char* slotA = ws + 72*MB;              // 72..136MB
    char* slotB = ws + 136*MB;             // 136..200MB
    bf16* qkvw_b = (bf16*)(ws + 200*MB);
    bf16* outw_b = qkvw_b + (size_t)3072 * 1024;
    bf16* fc1w_b = outw_b + (size_t)1024 * 1024;
    bf16* fc2w_b = fc1w_b + (size_t)2048 * 1024;

    bf16* ek   = (bf16*)slotA;             // [2048, 8192]
    bf16* vv   = (bf16*)(slotA + 32*MB);
    bf16* EKt  = (bf16*)slotB;             // [8192, 2048] then EKVt adjacent
    bf16* EKVt = (bf16*)(slotB + 32*MB);
    bf16* Ccat = (bf16*)slotA;             // [2048, 16384]
    bf16* Y    = (bf16*)slotB;             // [2048, 8192]
    bf16* x12  = (bf16*)slotA;             // [16384, 2048]
    bf16* ffin = (bf16*)(slotB + 32*MB);   // [16384, 1024]

    ln_kernel<<<MROWS, 256, 0, stream>>>(data, h);
    expw_kernel<<<4096, 256, 0, stream>>>(pos_b, Wb, T_DIM * T_DIM / 4);
    cvt_kernel<<<3072, 256, 0, stream>>>(qkv_w, qkvw_b, 3072 * 1024 / 4);
    cvt_kernel<<<1024, 256, 0, stream>>>(out_w, outw_b, 1024 * 1024 / 4);
    cvt_kernel<<<2048, 256, 0, stream>>>(fc1_w, fc1w_b, 2048 * 1024 / 4);
    cvt_kernel<<<1024, 256, 0, stream>>>(fc2_w, fc2w_b, 1024 * 1024 / 4);

    // QKV projection -> sigmoid(q), exp(k), v
    gemm8<MROWS, 3072, 1024, EPI_QKV><<<dim3(12, 64), 512, 0, stream>>>(
        h, qkvw_b, qkv_b, sq, ek, vv, nullptr, nullptr);

    // ek, ek*v transposed to [8192,2048]
    transpose_ekv<<<dim3(128, 32), 256, 0, stream>>>(
        (const unsigned short*)ek, (const unsigned short*)vv,
        (unsigned short*)EKt, (unsigned short*)EKVt);

    // one big GEMM: Ccat[t, 0..8191]=den, [8192..16383]=num
    gemm8<T_DIM, 2 * N8, T_DIM, EPI_STORE_BF16><<<dim3(64, 8), 512, 0, stream>>>(
        Wb, EKt, nullptr, Ccat, nullptr, nullptr, nullptr, nullptr);

    // Y = sigmoid(q) * num/den
    attn_combine<<<8192, 256, 0, stream>>>(
        (const unsigned short*)Ccat, (const unsigned short*)sq, (unsigned short*)Y);

    // out projection -> aft stored in d_out (f32)
    gemm8<MROWS, 1024, 1024, EPI_BIAS_F32><<<dim3(4, 64), 512, 0, stream>>>(
        Y, outw_b, out_b, out, nullptr, nullptr, nullptr, nullptr);

    // fc1 (both halves) -> x12 bf16 [16384, 2048]
    gemm8<MROWS, 2048, 1024, EPI_BIAS_BF16><<<dim3(8, 64), 512, 0, stream>>>(
        h, fc1w_b, fc1_b, x12, nullptr, nullptr, nullptr, nullptr);

    // ffin = x1 * mish(gate)
    glu_combine<<<8192, 256, 0, stream>>>(
        (const unsigned short*)x12, (unsigned short*)ffin);

    // fc2 + residual: out = c + data + aft(d_out)
    gemm8<MROWS, 1024, 1024, EPI_FC2SUM><<<dim3(4, 64), 512, 0, stream>>>(
        ffin, fc2w_b, fc2_b, out, nullptr, nullptr, data, out);
}

// Round 4
// 719.714 us; speedup vs baseline: 1.3866x; 1.0122x over previous
//
#include <hip/hip_runtime.h>
#include <hip/hip_bf16.h>
#include <cmath>
#include <cstdint>

using bf16 = __hip_bfloat16;
typedef __attribute__((ext_vector_type(8))) short short8;
typedef __attribute__((ext_vector_type(4))) float f32x4;
typedef __attribute__((ext_vector_type(4))) unsigned short ushort4v;

#define T_DIM 2048
#define B_DIM 8
#define D_DIM 1024
#define MROWS (T_DIM*B_DIM)   // 16384
#define N8 (B_DIM*D_DIM)      // 8192

__device__ __forceinline__ float b2f(bf16 x) { return __bfloat162float(x); }
__device__ __forceinline__ bf16  f2b(float x) { return __float2bfloat16(x); }
__device__ __forceinline__ float us2f(unsigned short u) {
    union { unsigned int i; float f; } x; x.i = ((unsigned int)u) << 16; return x.f;
}
__device__ __forceinline__ unsigned short f2us(float f) {
    bf16 b = __float2bfloat16(f);
    return *(unsigned short*)&b;
}

// async global->LDS, 16B per lane. LDS dest must be wave-uniform base + lane*16.
__device__ __forceinline__ void gload_lds16(const bf16* g, char* l) {
    __builtin_amdgcn_global_load_lds(
        (const __attribute__((address_space(1))) unsigned int*)g,
        (__attribute__((address_space(3))) unsigned int*)l,
        16, 0, 0);
}

// ---------------- LayerNorm: f32 [16384,1024] -> bf16 ----------------
__global__ __launch_bounds__(256) void ln_kernel(const float* __restrict__ x,
                                                 bf16* __restrict__ h) {
    const int row = blockIdx.x;
    const int tid = threadIdx.x;
    const float4 v = ((const float4*)(x + (size_t)row * D_DIM))[tid];
    float s1 = v.x + v.y + v.z + v.w;
    float s2 = v.x*v.x + v.y*v.y + v.z*v.z + v.w*v.w;
    #pragma unroll
    for (int off = 32; off > 0; off >>= 1) {
        s1 += __shfl_down(s1, off);
        s2 += __shfl_down(s2, off);
    }
    __shared__ float red[8];
    const int lane = tid & 63, wv = tid >> 6;
    if (lane == 0) { red[wv*2] = s1; red[wv*2+1] = s2; }
    __syncthreads();
    s1 = red[0] + red[2] + red[4] + red[6];
    s2 = red[1] + red[3] + red[5] + red[7];
    const float mean = s1 * (1.0f / D_DIM);
    const float var  = s2 * (1.0f / D_DIM) - mean * mean;
    const float rstd = rsqrtf(var + 1.1754943508222875e-38f);
    bf16* hr = h + (size_t)row * D_DIM + tid * 4;
    hr[0] = f2b((v.x - mean) * rstd);
    hr[1] = f2b((v.y - mean) * rstd);
    hr[2] = f2b((v.z - mean) * rstd);
    hr[3] = f2b((v.w - mean) * rstd);
}

// ---------------- exp(pos_bias) f32 -> bf16 ----------------
__global__ __launch_bounds__(256) void expw_kernel(const float* __restrict__ p,
                                                   bf16* __restrict__ w, int n4) {
    const int i = blockIdx.x * 256 + threadIdx.x;
    if (i < n4) {
        const float4 v = ((const float4*)p)[i];
        bf16* o = w + (size_t)i * 4;
        o[0] = f2b(expf(v.x)); o[1] = f2b(expf(v.y));
        o[2] = f2b(expf(v.z)); o[3] = f2b(expf(v.w));
    }
}

// ---------------- f32 -> bf16 convert ----------------
__global__ __launch_bounds__(256) void cvt_kernel(const float* __restrict__ p,
                                                  bf16* __restrict__ w, int n4) {
    const int i = blockIdx.x * 256 + threadIdx.x;
    if (i < n4) {
        const float4 v = ((const float4*)p)[i];
        bf16* o = w + (size_t)i * 4;
        o[0] = f2b(v.x); o[1] = f2b(v.y); o[2] = f2b(v.z); o[3] = f2b(v.w);
    }
}

// ---------------- transpose [2048,8192] -> [8192,2048]; EKVt = ek*v ----------------
__global__ __launch_bounds__(256) void transpose_ekv(
        const unsigned short* __restrict__ ek, const unsigned short* __restrict__ vv,
        unsigned short* __restrict__ EKt, unsigned short* __restrict__ EKVt) {
    __shared__ unsigned short le[64][68];
    __shared__ unsigned short lv[64][68];
    const int t0 = blockIdx.y * 64;
    const int n0 = blockIdx.x * 64;
    const int tid = threadIdx.x;
    const int r = tid >> 4;
    const int c = tid & 15;
    #pragma unroll
    for (int rr = 0; rr < 4; rr++) {
        const int row = rr * 16 + r;
        const size_t gi = (size_t)(t0 + row) * N8 + n0 + c * 4;
        const ushort4v e = *(const ushort4v*)(ek + gi);
        const ushort4v v = *(const ushort4v*)(vv + gi);
        *(ushort4v*)&le[row][c * 4] = e;
        *(ushort4v*)&lv[row][c * 4] = v;
    }
    __syncthreads();
    #pragma unroll
    for (int rr = 0; rr < 4; rr++) {
        const int nrow = rr * 16 + r;
        ushort4v eo, evo;
        #pragma unroll
        for (int j = 0; j < 4; j++) {
            const int tl = c * 4 + j;
            const unsigned short e = le[tl][nrow];
            const unsigned short v = lv[tl][nrow];
            eo[j]  = e;
            evo[j] = f2us(us2f(e) * us2f(v));
        }
        const size_t go = (size_t)(n0 + nrow) * T_DIM + t0 + c * 4;
        *(ushort4v*)(EKt + go)  = eo;
        *(ushort4v*)(EKVt + go) = evo;
    }
}

// ---------------- attn combine: Y = sigmoid(q) * num/den ----------------
__global__ __launch_bounds__(256) void attn_combine(
        const unsigned short* __restrict__ C, const unsigned short* __restrict__ sq,
        unsigned short* __restrict__ Y) {
    const size_t i8 = (size_t)blockIdx.x * 256 + threadIdx.x;
    const size_t j0 = i8 * 8;
    const int t = (int)(j0 >> 13);
    const int u = (int)(j0 & 8191);
    const size_t cbase = (size_t)t * 16384 + u;
    const short8 den = *(const short8*)(C + cbase);
    const short8 num = *(const short8*)(C + cbase + 8192);
    const short8 s   = *(const short8*)(sq + j0);
    short8 y;
    #pragma unroll
    for (int j = 0; j < 8; j++) {
        const float n = us2f((unsigned short)num[j]);
        const float d = us2f((unsigned short)den[j]);
        const float sv = us2f((unsigned short)s[j]);
        y[j] = (short)f2us(sv * (n / d));
    }
    *(short8*)(Y + j0) = y;
}

// ---------------- GLU combine: ffin = x1 * mish(gate) ----------------
__global__ __launch_bounds__(256) void glu_combine(
        const unsigned short* __restrict__ x12, unsigned short* __restrict__ ffin) {
    const size_t i8 = (size_t)blockIdx.x * 256 + threadIdx.x;
    const size_t j0 = i8 * 8;
    const int row = (int)(j0 >> 10);
    const int d = (int)(j0 & 1023);
    const size_t base = (size_t)row * 2048 + d;
    const short8 x1v = *(const short8*)(x12 + base);
    const short8 gv  = *(const short8*)(x12 + base + 1024);
    short8 o;
    #pragma unroll
    for (int j = 0; j < 8; j++) {
        const float x1 = us2f((unsigned short)x1v[j]);
        const float g  = us2f((unsigned short)gv[j]);
        const float sp = (g > 20.f) ? g : log1pf(expf(g));
        o[j] = (short)f2us(x1 * (g * tanhf(sp)));
    }
    *(short8*)(ffin + j0) = o;
}

// ================= 256x256 8-phase GEMM (T1+T2+T3+T4+T5) ====================
// C[m,n] = sum_k A[m,k]*Bt[n,k].  512 thr = 8 waves (2x4), BK=64, 2 K-tiles/iter.
// LDS 128KB = 2 bufs x 4 blocks (A0,A1,B0,B1) of 16KB.
// Block layout: [ksub(2) x 8KB][row(128) x 64B][kc(32) x bf16]; physical byte
// addr = linear ^ ((linear>>9)&1)<<5  (64B rows -> row bit0 feeds bank bit6;
// XOR spreads to exactly 8 lanes/bank per ds_read_b128 = minimum, conflict-free).
// DMA dest linear; source k pre-swizzled (inverse involution); read k swizzled.
enum { EPI_QKV = 0, EPI_BIAS_F32 = 1, EPI_FC2SUM = 2, EPI_STORE_BF16 = 3, EPI_BIAS_BF16 = 4 };

#define BAR() __builtin_amdgcn_s_barrier()

#define RD_A(ABASE, MOFF)                                                       \
    _Pragma("unroll")                                                           \
    for (int m = 0; m < 4; m++) {                                               \
        a[m][0] = *(const short8*)(lds + (ABASE) + (MOFF + m) * 1024);          \
        a[m][1] = *(const short8*)(lds + (ABASE) + (MOFF + m) * 1024 + 8192);   \
    }

#define RD_B(BBASE, NOFF, BREG)                                                 \
    _Pragma("unroll")                                                           \
    for (int n = 0; n < 2; n++) {                                               \
        BREG[n][0] = *(const short8*)(lds + (BBASE) + (NOFF + n) * 1024);       \
        BREG[n][1] = *(const short8*)(lds + (BBASE) + (NOFF + n) * 1024 + 8192);\
    }

#define MFMA_QUAD(MB, NB, BREG)                                               \
    __builtin_amdgcn_s_setprio(1);                                            \
    _Pragma("unroll")                                                         \
    for (int m = 0; m < 4; m++) {                                             \
        _Pragma("unroll")                                                     \
        for (int n = 0; n < 2; n++) {                                         \
            acc[MB + m][NB + n] = __builtin_amdgcn_mfma_f32_16x16x32_bf16(    \
                a[m][0], BREG[n][0], acc[MB + m][NB + n], 0, 0, 0);           \
            acc[MB + m][NB + n] = __builtin_amdgcn_mfma_f32_16x16x32_bf16(    \
                a[m][1], BREG[n][1], acc[MB + m][NB + n], 0, 0, 0);           \
        }                                                                     \
    }                                                                         \
    __builtin_amdgcn_s_setprio(0);

template <int M, int N, int K, int EPI>
__global__ __launch_bounds__(512, 2)
void gemm8(const bf16* __restrict__ A, const bf16* __restrict__ Bt,
           const float* __restrict__ bias,
           void* __restrict__ o0, void* __restrict__ o1, void* __restrict__ o2,
           const float* __restrict__ e1, const float* __restrict__ e2) {
    constexpr int NK = K / 64;
    constexpr int NIT = NK / 2;
    constexpr int KMASK = NK - 1;
    __shared__ char lds[131072];
    const int tid = threadIdx.x;
    const int lane = tid & 63;
    const int wid = tid >> 6;
    const int wr = wid >> 2, wc = wid & 3;
    const int lr = lane & 15;

    // XCD-aware bijective swizzle (all grids are multiples of 8 blocks)
    const int nwg = gridDim.x * gridDim.y;
    int lin = blockIdx.y * gridDim.x + blockIdx.x;
    lin = (lin & 7) * (nwg >> 3) + (lin >> 3);
    const int bx = lin % gridDim.x, by = lin / gridDim.x;
    const int m0 = by * 256, n0 = bx * 256;

    // staging constants: thread tid fetches the logical element whose swizzled
    // physical slot is tid*16 (linear DMA dest).
    const int srow  = tid >> 2;                                    // 0..127
    const int skcol = ((tid & 3) * 8) ^ (((tid >> 5) & 1) << 4);   // elements
    const int sdst  = tid * 16;                                    // bytes

    // read-side swizzle: 16B slot (lane>>4), XOR bit5 with row bit3 (lane bit3)
    const int ck = ((lane >> 4) * 16) ^ (((lane >> 3) & 1) << 5);
    const int abase0 = wr * 16384 + lr * 64 + ck;
    const int abase1 = 65536 + abase0;
    const int bbase0 = 32768 + (wc >> 1) * 16384 + (wc & 1) * 4096 + lr * 64 + ck;
    const int bbase1 = 65536 + bbase0;

    auto STAGE = [&](const bf16* P, int r0, int kt, int ldsoff) {
        const bf16* src = P + (size_t)(r0 + srow) * K + kt + skcol;
        gload_lds16(src,      lds + ldsoff + sdst);
        gload_lds16(src + 32, lds + ldsoff + 8192 + sdst);
    };

    f32x4 acc[8][4] = {};
    short8 a[4][2], blo[2][2], bhi[2][2];

    // prologue: tile0 (all 4 blocks) + B0(1), A0(1); leave last 2 blocks in flight
    STAGE(A,  m0,       0, 0);
    STAGE(A,  m0 + 128, 0, 16384);
    STAGE(Bt, n0,       0, 32768);
    STAGE(Bt, n0 + 128, 0, 49152);
    STAGE(Bt, n0,      64, 65536 + 32768);
    STAGE(A,  m0,      64, 65536);
    asm volatile("s_waitcnt vmcnt(4)");
    BAR();

    for (int i = 0; i < NIT; ++i) {
        const int t1k = ((2 * i + 1) & KMASK) * 64;
        const int t2k = ((2 * i + 2) & KMASK) * 64;
        const int t3k = ((2 * i + 3) & KMASK) * 64;
        // p1: (mlo,nlo) of tile U(buf0); stage B1(V)
        RD_A(abase0, 0); RD_B(bbase0, 0, blo);
        STAGE(Bt, n0 + 128, t1k, 65536 + 49152);
        BAR(); MFMA_QUAD(0, 0, blo); BAR();
        // p2: (mlo,nhi); stage A1(V)
        RD_B(bbase0, 2, bhi);
        STAGE(A, m0 + 128, t1k, 65536 + 16384);
        BAR(); MFMA_QUAD(0, 2, bhi); BAR();
        // p3: (mhi,nhi); stage B0(t+2)
        RD_A(abase0, 4);
        STAGE(Bt, n0, t2k, 32768);
        BAR(); MFMA_QUAD(4, 2, bhi); BAR();
        // p4: (mhi,nlo); stage A0(t+2); counted wait -> tile V fully landed
        STAGE(A, m0, t2k, 0);
        asm volatile("s_waitcnt vmcnt(4)");
        BAR(); MFMA_QUAD(4, 0, blo); BAR();
        // p5: (mlo,nlo) of tile V(buf1); stage A1(t+2)
        RD_A(abase1, 0); RD_B(bbase1, 0, blo);
        STAGE(A, m0 + 128, t2k, 16384);
        BAR(); MFMA_QUAD(0, 0, blo); BAR();
        // p6: (mlo,nhi); stage B1(t+2)
        RD_B(bbase1, 2, bhi);
        STAGE(Bt, n0 + 128, t2k, 49152);
        BAR(); MFMA_QUAD(0, 2, bhi); BAR();
        // p7: (mhi,nhi); stage B0(t+3)
        RD_A(abase1, 4);
        STAGE(Bt, n0, t3k, 65536 + 32768);
        BAR(); MFMA_QUAD(4, 2, bhi); BAR();
        // p8: (mhi,nlo); stage A0(t+3); counted wait -> tile t+2 fully landed
        STAGE(A, m0, t3k, 65536);
        asm volatile("s_waitcnt vmcnt(4)");
        BAR(); MFMA_QUAD(4, 0, blo); BAR();
    }
    asm volatile("s_waitcnt vmcnt(0)");  // drain DMA before LDS teardown

    // epilogue
    const int rb = (lane >> 4) * 4;
    #pragma unroll
    for (int mm = 0; mm < 8; mm++) {
        #pragma unroll
        for (int nn = 0; nn < 4; nn++) {
            const int col = n0 + wc * 64 + nn * 16 + lr;
            float bv = 0.f;
            if constexpr (EPI != EPI_STORE_BF16) bv = bias[col];
            const int row0 = m0 + wr * 128 + mm * 16 + rb;
            #pragma unroll
            for (int r = 0; r < 4; r++) {
                const int row = row0 + r;
                const float c = acc[mm][nn][r] + bv;
                if constexpr (EPI == EPI_QKV) {
                    const int seg = col >> 10;
                    const int nc = col & 1023;
                    const size_t idx = (size_t)row * 1024 + nc;
                    if (seg == 0)      ((bf16*)o0)[idx] = f2b(1.f / (1.f + expf(-c)));
                    else if (seg == 1) ((bf16*)o1)[idx] = f2b(expf(c));
                    else               ((bf16*)o2)[idx] = f2b(c);
                } else if constexpr (EPI == EPI_BIAS_F32) {
                    ((float*)o0)[(size_t)row * N + col] = c;
                } else if constexpr (EPI == EPI_STORE_BF16 || EPI == EPI_BIAS_BF16) {
                    ((bf16*)o0)[(size_t)row * N + col] = f2b(c);
                } else { // EPI_FC2SUM
                    const size_t idx = (size_t)row * N + col;
                    ((float*)o0)[idx] = c + e1[idx] + e2[idx];
                }
            }
        }
    }
}

// ---------------- launch ----------------
extern "C" void kernel_launch(void* const* d_in, const int* in_sizes, int n_in,
                              void* d_out, int out_size, void* d_ws, size_t ws_size,
                              hipStream_t stream) {
    const float* data  = (const float*)d_in[0];
    const float* qkv_w = (const float*)d_in[1];
    const float* qkv_b = (const float*)d_in[2];
    const float* pos_b = (const float*)d_in[3];
    const float* out_w = (const float*)d_in[4];
    const float* out_b = (const float*)d_in[5];
    const float* fc1_w = (const float*)d_in[6];
    const float* fc1_b = (const float*)d_in[7];
    const float* fc2_w = (const float*)d_in[8];
    const float* fc2_b = (const float*)d_in[9];
    float* out = (float*)d_out;

    char* ws = (char*)d_ws;
    const size_t MB = 1024ull * 1024ull;
    bf16* h    = (bf16*)(ws);              // 0..32MB
    bf16* Wb   = (bf16*)(ws + 32*MB);      // 32..40MB
    bf16* sq   = (bf16*)(ws + 40*MB);      // 40..72MB
    char* slotA = ws + 72*MB;              // 72..136MB
    char* slotB = ws + 136*MB;             // 136..200MB
    bf16* qkvw_b = (bf16*)(ws + 200*MB);
    bf16* outw_b = qkvw_b + (size_t)3072 * 1024;
    bf16* fc1w_b = outw_b + (size_t)1024 * 1024;
    bf16* fc2w_b = fc1w_b + (size_t)2048 * 1024;

    bf16* ek   = (bf16*)slotA;             // [2048, 8192]
    bf16* vv   = (bf16*)(slotA + 32*MB);
    bf16* EKt  = (bf16*)slotB;             // [8192, 2048] then EKVt adjacent
    bf16* EKVt = (bf16*)(slotB + 32*MB);
    bf16* Ccat = (bf16*)slotA;             // [2048, 16384]
    bf16* Y    = (bf16*)slotB;             // [2048, 8192]
    bf16* x12  = (bf16*)slotA;             // [16384, 2048]
    bf16* ffin = (bf16*)(slotB + 32*MB);   // [16384, 1024]

    ln_kernel<<<MROWS, 256, 0, stream>>>(data, h);
    expw_kernel<<<4096, 256, 0, stream>>>(pos_b, Wb, T_DIM * T_DIM / 4);
    cvt_kernel<<<3072, 256, 0, stream>>>(qkv_w, qkvw_b, 3072 * 1024 / 4);
    cvt_kernel<<<1024, 256, 0, stream>>>(out_w, outw_b, 1024 * 1024 / 4);
    cvt_kernel<<<2048, 256, 0, stream>>>(fc1_w, fc1w_b, 2048 * 1024 / 4);
    cvt_kernel<<<1024, 256, 0, stream>>>(fc2_w, fc2w_b, 1024 * 1024 / 4);

    // QKV projection -> sigmoid(q), exp(k), v
    gemm8<MROWS, 3072, 1024, EPI_QKV><<<dim3(12, 64), 512, 0, stream>>>(
        h, qkvw_b, qkv_b, sq, ek, vv, nullptr, nullptr);

    // ek, ek*v transposed to [8192,2048]
    transpose_ekv<<<dim3(128, 32), 256, 0, stream>>>(
        (const unsigned short*)ek, (const unsigned short*)vv,
        (unsigned short*)EKt, (unsigned short*)EKVt);

    // one big GEMM: Ccat[t, 0..8191]=den, [8192..16383]=num
    gemm8<T_DIM, 2 * N8, T_DIM, EPI_STORE_BF16><<<dim3(64, 8), 512, 0, stream>>>(
        Wb, EKt, nullptr, Ccat, nullptr, nullptr, nullptr, nullptr);

    // Y = sigmoid(q) * num/den
    attn_combine<<<8192, 256, 0, stream>>>(
        (const unsigned short*)Ccat, (const unsigned short*)sq, (unsigned short*)Y);

    // out projection -> aft stored in d_out (f32)
    gemm8<MROWS, 1024, 1024, EPI_BIAS_F32><<<dim3(4, 64), 512, 0, stream>>>(
        Y, outw_b, out_b, out, nullptr, nullptr, nullptr, nullptr);

    // fc1 (both halves) -> x12 bf16 [16384, 2048]
    gemm8<MROWS, 2048, 1024, EPI_BIAS_BF16><<<dim3(8, 64), 512, 0, stream>>>(
        h, fc1w_b, fc1_b, x12, nullptr, nullptr, nullptr, nullptr);

    // ffin = x1 * mish(gate)
    glu_combine<<<8192, 256, 0, stream>>>(
        (const unsigned short*)x12, (unsigned short*)ffin);

    // fc2 + residual: out = c + data + aft(d_out)
    gemm8<MROWS, 1024, 1024, EPI_FC2SUM><<<dim3(4, 64), 512, 0, stream>>>(
        ffin, fc2w_b, fc2_b, out, nullptr, nullptr, data, out);
}